// Round 3
// baseline (572.746 us; speedup 1.0000x reference)
//
#include <hip/hip_runtime.h>
#include <hip/hip_bf16.h>
#include <stdint.h>

typedef unsigned short u16;
typedef unsigned int   u32;

#define N_NODES 50000
#define N_EDGES 400000
#define DDIM    512
#define KTOT    1024          // fused K: [xb | meanNeg]
#define BM      224           // 224 * 224 blocks = 50176 >= 50000, single-round grid
#define BMS     256           // staged A rows (rounded up, rows 224-255 clamped)
#define BN      512           // full N: A panel read exactly once
#define BK      32
#define NT      (KTOT / BK)   // 32 K-tiles
#define MTILES  ((N_NODES + BM - 1) / BM)   // 224 blocks (= 87.5% of 256 CUs, one round)

typedef __attribute__((ext_vector_type(8))) __bf16 bf16x8;
typedef __attribute__((ext_vector_type(4))) float  f32x4;

#define S_VMCNT(n) do { asm volatile("s_waitcnt vmcnt(" #n ")" ::: "memory"); \
                        __builtin_amdgcn_sched_barrier(0); } while (0)
#define S_LGKM0()  do { asm volatile("s_waitcnt lgkmcnt(0)" ::: "memory"); \
                        __builtin_amdgcn_sched_barrier(0); } while (0)

// ---------- helpers ----------
__device__ __forceinline__ float bflo(u32 d) { return __builtin_bit_cast(float, d << 16); }
__device__ __forceinline__ float bfhi(u32 d) { return __builtin_bit_cast(float, d & 0xffff0000u); }
__device__ __forceinline__ u16 f2bf(float f) {
    u32 u = __builtin_bit_cast(u32, f);
    u32 r = u + 0x7fffu + ((u >> 16) & 1u);   // RNE; inputs finite
    return (u16)(r >> 16);
}
__device__ __forceinline__ u32 pack2(float a, float b) {
    return (u32)f2bf(a) | ((u32)f2bf(b) << 16);
}
__device__ __forceinline__ void gload_lds16(const void* g, void* l) {
    __builtin_amdgcn_global_load_lds(
        (const __attribute__((address_space(1))) void*)g,
        (__attribute__((address_space(3))) void*)l, 16, 0, 0);
}

// ---------- 0. x (f32) -> Acat[:, 0:512] (bf16, row stride 1024) ----------
__global__ void cvt_k(const float* __restrict__ x, u16* __restrict__ Acat) {
    int i = blockIdx.x * 256 + threadIdx.x;     // one thread = 8 elements
    int node = i >> 6, c8 = i & 63;             // 64 threads per node-row
    const float4* p = (const float4*)(x + (size_t)node * DDIM + c8 * 8);
    float4 a = p[0], b = p[1];
    uint4 o;
    o.x = pack2(a.x, a.y); o.y = pack2(a.z, a.w);
    o.z = pack2(b.x, b.y); o.w = pack2(b.z, b.w);
    *(uint4*)(Acat + (size_t)node * KTOT + c8 * 8) = o;
}

// ---------- 1. histogram of dst ----------
__global__ void hist_k(const int* __restrict__ dst, int* __restrict__ counts) {
    int e = blockIdx.x * 256 + threadIdx.x;
    if (e < N_EDGES) atomicAdd(&counts[dst[e]], 1);
}

// ---------- 2. three-phase exclusive scan (49 chunks of 1024) ----------
#define NCHUNK 49
__global__ __launch_bounds__(1024) void scanA_k(const int* __restrict__ counts, int* __restrict__ csum) {
    __shared__ int ws[16];
    int t = threadIdx.x, b = blockIdx.x;
    int i = b * 1024 + t;
    int v = (i < N_NODES) ? counts[i] : 0;
    for (int d = 32; d; d >>= 1) v += __shfl_down(v, d);
    if ((t & 63) == 0) ws[t >> 6] = v;
    __syncthreads();
    if (t < 16) {
        int s = ws[t];
        for (int d = 8; d; d >>= 1) s += __shfl_down(s, d);
        if (t == 0) csum[b] = s;
    }
}
__global__ void scanB_k(int* __restrict__ csum) {   // 64 threads, exclusive in-place
    int t = threadIdx.x;
    int v = (t < NCHUNK) ? csum[t] : 0;
    int s = v;
    for (int d = 1; d < 64; d <<= 1) { int u = __shfl_up(s, d); if (t >= d) s += u; }
    if (t < NCHUNK) csum[t] = s - v;
}
__global__ __launch_bounds__(1024) void scanC_k(const int* __restrict__ counts, const int* __restrict__ csum,
                                                int* __restrict__ offsets, int* __restrict__ cursor) {
    __shared__ int wsum[16];
    int t = threadIdx.x, b = blockIdx.x;
    int i = b * 1024 + t;
    int lane = t & 63, w = t >> 6;
    int v = (i < N_NODES) ? counts[i] : 0;
    int s = v;
    for (int d = 1; d < 64; d <<= 1) { int u = __shfl_up(s, d); if (lane >= d) s += u; }
    if (lane == 63) wsum[w] = s;
    __syncthreads();
    if (t < 16) {
        int ww = wsum[t], ss = ww;
        for (int d = 1; d < 16; d <<= 1) { int u = __shfl_up(ss, d); if (t >= d) ss += u; }
        wsum[t] = ss - ww;
    }
    __syncthreads();
    int excl = (s - v) + wsum[w] + csum[b];
    if (i < N_NODES) { offsets[i] = excl; cursor[i] = excl; }
}

// ---------- 3. fill CSR ----------
__global__ void fill_k(const int* __restrict__ src, const int* __restrict__ dst,
                       int* __restrict__ cursor, int* __restrict__ esrc) {
    int e = blockIdx.x * 256 + threadIdx.x;
    if (e < N_EDGES) {
        int d = dst[e];
        int p = atomicAdd(&cursor[d], 1);
        esrc[p] = src[e];
    }
}

// ---------- 4. prep weights: Wcat[n][k] = bf16(W1+W2), Wcat[n][512+k] = bf16(W2) ----------
__global__ void prepw_k(const float* __restrict__ W1, const float* __restrict__ W2,
                        const float* __restrict__ b1, const float* __restrict__ b2,
                        u16* __restrict__ Wcat, float* __restrict__ b12) {
    int idx = blockIdx.x * 256 + threadIdx.x;          // = k*512 + n
    int k = idx >> 9, n = idx & 511;
    float w1 = W1[idx], w2 = W2[idx];
    Wcat[(size_t)n * KTOT + k]       = f2bf(w1 + w2);
    Wcat[(size_t)n * KTOT + 512 + k] = f2bf(w2);
    if (idx < 512) b12[idx] = b1[idx] + b2[idx];
}

// ---------- 5. aggregate: Acat[:, 512:1024] = bf16(-mean) ----------
__device__ __forceinline__ void addrow(float* acc, uint4 v) {
    acc[0] += bflo(v.x); acc[1] += bfhi(v.x);
    acc[2] += bflo(v.y); acc[3] += bfhi(v.y);
    acc[4] += bflo(v.z); acc[5] += bfhi(v.z);
    acc[6] += bflo(v.w); acc[7] += bfhi(v.w);
}
__global__ __launch_bounds__(256) void agg_k(u16* Acat,
                                             const int* __restrict__ offsets,
                                             const int* __restrict__ counts,
                                             const int* __restrict__ esrc) {
    int nid = blockIdx.x * 4 + (threadIdx.x >> 6);
    if (nid >= N_NODES) return;
    int lane = threadIdx.x & 63;
    int off = offsets[nid], deg = counts[nid];
    float acc[8] = {0, 0, 0, 0, 0, 0, 0, 0};
    int e = 0;
    // 8-deep unroll: 8 independent 16B loads in flight per lane
    for (; e + 7 < deg; e += 8) {
        int s[8];
        #pragma unroll
        for (int u = 0; u < 8; u++) s[u] = esrc[off + e + u];
        uint4 v[8];
        #pragma unroll
        for (int u = 0; u < 8; u++)
            v[u] = *(const uint4*)(Acat + (size_t)s[u] * KTOT + lane * 8);
        #pragma unroll
        for (int u = 0; u < 8; u++) addrow(acc, v[u]);
    }
    for (; e + 3 < deg; e += 4) {
        int s0 = esrc[off + e], s1 = esrc[off + e + 1];
        int s2 = esrc[off + e + 2], s3 = esrc[off + e + 3];
        uint4 v0 = *(const uint4*)(Acat + (size_t)s0 * KTOT + lane * 8);
        uint4 v1 = *(const uint4*)(Acat + (size_t)s1 * KTOT + lane * 8);
        uint4 v2 = *(const uint4*)(Acat + (size_t)s2 * KTOT + lane * 8);
        uint4 v3 = *(const uint4*)(Acat + (size_t)s3 * KTOT + lane * 8);
        addrow(acc, v0); addrow(acc, v1); addrow(acc, v2); addrow(acc, v3);
    }
    for (; e < deg; e++) {
        int s0 = esrc[off + e];
        addrow(acc, *(const uint4*)(Acat + (size_t)s0 * KTOT + lane * 8));
    }
    float scale = (deg > 0) ? (-1.0f / (float)deg) : 0.0f;
    uint4 o;
    o.x = pack2(acc[0] * scale, acc[1] * scale);
    o.y = pack2(acc[2] * scale, acc[3] * scale);
    o.z = pack2(acc[4] * scale, acc[5] * scale);
    o.w = pack2(acc[6] * scale, acc[7] * scale);
    *(uint4*)(Acat + (size_t)nid * KTOT + 512 + lane * 8) = o;
}

// ---------- 6. GEMM: out = Acat @ Wcat^T + b12 (K=1024, masked passthrough) ----------
// BM=224 x BN=512(full N), BK=32, 3-deep LDS pipeline (144 KB), 8 waves (2M x 4N),
// per-wave 112x128 output (acc[7][8]). Single sync point per K-tile:
//   { ds_read af[7],bf[8]; stage(t+2) into the idle 3rd buffer; 56 MFMA;
//     lgkm(0); vmcnt(6) [retire tile t+1, keep t+2 in flight]; s_barrier }
// A panel read ONCE (no N-split); B (1 MB) L2-resident. Grid 224 = one round.
// BK=32 rows are 64 B; slot^=(row&3) swizzle keeps b128 reads at the conflict floor.
__global__ __launch_bounds__(512, 2) void gemm_k(const u16* __restrict__ Acat,
                                                 const float* __restrict__ x,
                                                 const u16* __restrict__ Wcat,
                                                 const float* __restrict__ b12,
                                                 const int* __restrict__ counts,
                                                 float* __restrict__ out) {
    __shared__ u16 As[3][BMS * BK];   // 3 x 16 KB
    __shared__ u16 Bs[3][BN * BK];    // 3 x 32 KB   (total 144 KB)

    const int m0 = blockIdx.x * BM;
    const int tid  = threadIdx.x;
    const int lane = tid & 63;
    const int wid  = tid >> 6;          // 0..7
    const int wm = wid >> 2, wn = wid & 3;
    const int quad = lane >> 4, lr = lane & 15;

    // staging: per issue, 512 threads cover 128 rows x 4 slots (64 B rows)
    const int srl   = tid >> 2;                       // row within 128-row group
    const int ssoff = (((tid & 3) ^ (srl & 3)) << 3); // pre-swizzled 16B slot (u16 units)
    int arow[2];
    #pragma unroll
    for (int q = 0; q < 2; q++) {
        int r = m0 + q * 128 + srl;
        arow[q] = (r < N_NODES) ? r : (N_NODES - 1);   // rows 224-255 are clamped filler
    }

    auto stage = [&](int t) {          // 6 loads/wave: 2 A + 4 B
        u16* A_c = As[t % 3]; u16* B_c = Bs[t % 3];
        const int k0 = t * BK;
        #pragma unroll
        for (int q = 0; q < 2; q++)
            gload_lds16(Acat + (size_t)arow[q] * KTOT + k0 + ssoff,
                        A_c + q * 4096 + wid * 512);
        #pragma unroll
        for (int q = 0; q < 4; q++)
            gload_lds16(Wcat + (size_t)(q * 128 + srl) * KTOT + k0 + ssoff,
                        B_c + q * 4096 + wid * 512);
    };

    const int rsw = (lr & 3);          // read-side slot swizzle
    auto ldA = [&](const u16* A_c, int mf) -> bf16x8 {
        int row = wm * 112 + mf * 16 + lr;
        return *(const bf16x8*)((const char*)A_c + row * 64 + ((quad ^ rsw) << 4));
    };
    auto ldB = [&](const u16* B_c, int nf) -> bf16x8 {
        int row = wn * 128 + nf * 16 + lr;
        return *(const bf16x8*)((const char*)B_c + row * 64 + ((quad ^ rsw) << 4));
    };

    f32x4 acc[7][8] = {};

    // prologue: tiles 0,1 in flight; wait tile 0 (6 newest outstanding = tile 1)
    stage(0); stage(1);
    S_VMCNT(6);
    __builtin_amdgcn_s_barrier();

    #pragma unroll 1
    for (int t = 0; t < NT; ++t) {
        const u16* A_c = As[t % 3];
        const u16* B_c = Bs[t % 3];

        bf16x8 af[7], bf[8];
        #pragma unroll
        for (int i = 0; i < 7; i++) af[i] = ldA(A_c, i);
        #pragma unroll
        for (int j = 0; j < 8; j++) bf[j] = ldB(B_c, j);

        if (t + 2 < NT) stage(t + 2);     // into buffer (t+2)%3 — idle this iter

        __builtin_amdgcn_s_setprio(1);
        #pragma unroll
        for (int i = 0; i < 7; i++)
            #pragma unroll
            for (int j = 0; j < 8; j++)
                acc[i][j] = __builtin_amdgcn_mfma_f32_16x16x32_bf16(af[i], bf[j], acc[i][j], 0, 0, 0);
        __builtin_amdgcn_s_setprio(0);

        S_LGKM0();                        // my reads of buf t done (region death)
        if (t < NT - 2) {
            S_VMCNT(6);                   // tile t+1 landed; t+2's 6 stay in flight
            __builtin_amdgcn_s_barrier();
        } else if (t == NT - 2) {
            S_VMCNT(0);                   // drain: last tile landed
            __builtin_amdgcn_s_barrier();
        }
        // t == NT-1: fall through to epilogue
    }

    // epilogue: C/D layout col=lr, row=quad*4+r ; f32 output, zero-degree passthrough
    #pragma unroll
    for (int i = 0; i < 7; i++) {
        #pragma unroll
        for (int r = 0; r < 4; r++) {
            int grow = m0 + wm * 112 + i * 16 + quad * 4 + r;
            if (grow >= N_NODES) continue;
            int cnt = counts[grow];
            #pragma unroll
            for (int j = 0; j < 8; j++) {
                int gcol = wn * 128 + j * 16 + lr;
                float v;
                if (cnt > 0) v = acc[i][j][r] + b12[gcol];
                else         v = x[(size_t)grow * DDIM + gcol];   // exact passthrough
                out[(size_t)grow * DDIM + gcol] = v;
            }
        }
    }
}

// ---------- launch ----------
extern "C" void kernel_launch(void* const* d_in, const int* in_sizes, int n_in,
                              void* d_out, int out_size, void* d_ws, size_t ws_size,
                              hipStream_t stream) {
    const float* x  = (const float*)d_in[0];
    const int* src  = (const int*)d_in[1];
    const int* dst  = (const int*)d_in[2];
    const float* W1 = (const float*)d_in[3];
    const float* b1 = (const float*)d_in[4];
    const float* W2 = (const float*)d_in[5];
    const float* b2 = (const float*)d_in[6];
    float* out = (float*)d_out;

    char* ws = (char*)d_ws;
    size_t o = 0;
    auto alloc = [&](size_t bytes) { char* p = ws + o; o += (bytes + 255) & ~(size_t)255; return p; };
    int* counts   = (int*)alloc((size_t)N_NODES * 4);
    int* offsets  = (int*)alloc((size_t)N_NODES * 4);
    int* cursor   = (int*)alloc((size_t)N_NODES * 4);
    int* csum     = (int*)alloc((size_t)NCHUNK * 4);
    int* esrc     = (int*)alloc((size_t)N_EDGES * 4);
    u16* Wcat     = (u16*)alloc((size_t)512 * KTOT * 2);
    float* b12    = (float*)alloc((size_t)512 * 4);
    u16* Acat     = (u16*)alloc((size_t)N_NODES * KTOT * 2);   // [xb | meanNeg], ~102.4 MB
    (void)ws_size; (void)n_in; (void)in_sizes; (void)out_size;

    hipMemsetAsync(counts, 0, (size_t)N_NODES * 4, stream);
    cvt_k<<<(N_NODES * 64) / 256, 256, 0, stream>>>(x, Acat);
    hist_k<<<(N_EDGES + 255) / 256, 256, 0, stream>>>(dst, counts);
    scanA_k<<<NCHUNK, 1024, 0, stream>>>(counts, csum);
    scanB_k<<<1, 64, 0, stream>>>(csum);
    scanC_k<<<NCHUNK, 1024, 0, stream>>>(counts, csum, offsets, cursor);
    fill_k<<<(N_EDGES + 255) / 256, 256, 0, stream>>>(src, dst, cursor, esrc);
    prepw_k<<<(512 * 512) / 256, 256, 0, stream>>>(W1, W2, b1, b2, Wcat, b12);
    agg_k<<<(N_NODES + 3) / 4, 256, 0, stream>>>(Acat, offsets, counts, esrc);
    gemm_k<<<dim3(MTILES), 512, 0, stream>>>(Acat, x, Wcat, b12, counts, out);
}

// Round 4
// 401.197 us; speedup vs baseline: 1.4276x; 1.4276x over previous
//
#include <hip/hip_runtime.h>
#include <hip/hip_bf16.h>
#include <stdint.h>

typedef unsigned short u16;
typedef unsigned int   u32;

#define N_NODES 50000
#define N_EDGES 400000
#define DDIM    512
#define KTOT    1024          // fused K: [xb | meanNeg]
#define BM      256
#define BMS     256
#define BN      256
#define BK      32
#define NT      (KTOT / BK)   // 32 K-tiles
#define MTILES  ((N_NODES + BM - 1) / BM)   // 196
#define NTILES  (DDIM / BN)                 // 2
#define NWG     (MTILES * NTILES)           // 392 = 8*49 exactly

typedef __attribute__((ext_vector_type(8))) __bf16 bf16x8;
typedef __attribute__((ext_vector_type(4))) float  f32x4;

#define S_VMCNT(n) do { asm volatile("s_waitcnt vmcnt(" #n ")" ::: "memory"); \
                        __builtin_amdgcn_sched_barrier(0); } while (0)
#define S_LGKM0()  do { asm volatile("s_waitcnt lgkmcnt(0)" ::: "memory"); \
                        __builtin_amdgcn_sched_barrier(0); } while (0)

// ---------- helpers ----------
__device__ __forceinline__ float bflo(u32 d) { return __builtin_bit_cast(float, d << 16); }
__device__ __forceinline__ float bfhi(u32 d) { return __builtin_bit_cast(float, d & 0xffff0000u); }
__device__ __forceinline__ u16 f2bf(float f) {
    u32 u = __builtin_bit_cast(u32, f);
    u32 r = u + 0x7fffu + ((u >> 16) & 1u);   // RNE; inputs finite
    return (u16)(r >> 16);
}
__device__ __forceinline__ u32 pack2(float a, float b) {
    return (u32)f2bf(a) | ((u32)f2bf(b) << 16);
}
__device__ __forceinline__ void gload_lds16(const void* g, void* l) {
    __builtin_amdgcn_global_load_lds(
        (const __attribute__((address_space(1))) void*)g,
        (__attribute__((address_space(3))) void*)l, 16, 0, 0);
}

// ---------- 0. x (f32) -> Acat[:, 0:512] (bf16, row stride 1024) ----------
__global__ void cvt_k(const float* __restrict__ x, u16* __restrict__ Acat) {
    int i = blockIdx.x * 256 + threadIdx.x;     // one thread = 8 elements
    int node = i >> 6, c8 = i & 63;             // 64 threads per node-row
    const float4* p = (const float4*)(x + (size_t)node * DDIM + c8 * 8);
    float4 a = p[0], b = p[1];
    uint4 o;
    o.x = pack2(a.x, a.y); o.y = pack2(a.z, a.w);
    o.z = pack2(b.x, b.y); o.w = pack2(b.z, b.w);
    *(uint4*)(Acat + (size_t)node * KTOT + c8 * 8) = o;
}

// ---------- 1. histogram of dst ----------
__global__ void hist_k(const int* __restrict__ dst, int* __restrict__ counts) {
    int e = blockIdx.x * 256 + threadIdx.x;
    if (e < N_EDGES) atomicAdd(&counts[dst[e]], 1);
}

// ---------- 2. three-phase exclusive scan (49 chunks of 1024) ----------
#define NCHUNK 49
__global__ __launch_bounds__(1024) void scanA_k(const int* __restrict__ counts, int* __restrict__ csum) {
    __shared__ int ws[16];
    int t = threadIdx.x, b = blockIdx.x;
    int i = b * 1024 + t;
    int v = (i < N_NODES) ? counts[i] : 0;
    for (int d = 32; d; d >>= 1) v += __shfl_down(v, d);
    if ((t & 63) == 0) ws[t >> 6] = v;
    __syncthreads();
    if (t < 16) {
        int s = ws[t];
        for (int d = 8; d; d >>= 1) s += __shfl_down(s, d);
        if (t == 0) csum[b] = s;
    }
}
__global__ void scanB_k(int* __restrict__ csum) {   // 64 threads, exclusive in-place
    int t = threadIdx.x;
    int v = (t < NCHUNK) ? csum[t] : 0;
    int s = v;
    for (int d = 1; d < 64; d <<= 1) { int u = __shfl_up(s, d); if (t >= d) s += u; }
    if (t < NCHUNK) csum[t] = s - v;
}
__global__ __launch_bounds__(1024) void scanC_k(const int* __restrict__ counts, const int* __restrict__ csum,
                                                int* __restrict__ offsets, int* __restrict__ cursor) {
    __shared__ int wsum[16];
    int t = threadIdx.x, b = blockIdx.x;
    int i = b * 1024 + t;
    int lane = t & 63, w = t >> 6;
    int v = (i < N_NODES) ? counts[i] : 0;
    int s = v;
    for (int d = 1; d < 64; d <<= 1) { int u = __shfl_up(s, d); if (lane >= d) s += u; }
    if (lane == 63) wsum[w] = s;
    __syncthreads();
    if (t < 16) {
        int ww = wsum[t], ss = ww;
        for (int d = 1; d < 16; d <<= 1) { int u = __shfl_up(ss, d); if (t >= d) ss += u; }
        wsum[t] = ss - ww;
    }
    __syncthreads();
    int excl = (s - v) + wsum[w] + csum[b];
    if (i < N_NODES) { offsets[i] = excl; cursor[i] = excl; }
}

// ---------- 3. fill CSR ----------
__global__ void fill_k(const int* __restrict__ src, const int* __restrict__ dst,
                       int* __restrict__ cursor, int* __restrict__ esrc) {
    int e = blockIdx.x * 256 + threadIdx.x;
    if (e < N_EDGES) {
        int d = dst[e];
        int p = atomicAdd(&cursor[d], 1);
        esrc[p] = src[e];
    }
}

// ---------- 4. prep weights: Wcat[n][k] = bf16(W1+W2), Wcat[n][512+k] = bf16(W2) ----------
__global__ void prepw_k(const float* __restrict__ W1, const float* __restrict__ W2,
                        const float* __restrict__ b1, const float* __restrict__ b2,
                        u16* __restrict__ Wcat, float* __restrict__ b12) {
    int idx = blockIdx.x * 256 + threadIdx.x;          // = k*512 + n
    int k = idx >> 9, n = idx & 511;
    float w1 = W1[idx], w2 = W2[idx];
    Wcat[(size_t)n * KTOT + k]       = f2bf(w1 + w2);
    Wcat[(size_t)n * KTOT + 512 + k] = f2bf(w2);
    if (idx < 512) b12[idx] = b1[idx] + b2[idx];
}

// ---------- 5. aggregate: Acat[:, 512:1024] = bf16(-mean) ----------
__device__ __forceinline__ void addrow(float* acc, uint4 v) {
    acc[0] += bflo(v.x); acc[1] += bfhi(v.x);
    acc[2] += bflo(v.y); acc[3] += bfhi(v.y);
    acc[4] += bflo(v.z); acc[5] += bfhi(v.z);
    acc[6] += bflo(v.w); acc[7] += bfhi(v.w);
}
__global__ __launch_bounds__(256) void agg_k(u16* Acat,
                                             const int* __restrict__ offsets,
                                             const int* __restrict__ counts,
                                             const int* __restrict__ esrc) {
    int nid = blockIdx.x * 4 + (threadIdx.x >> 6);
    if (nid >= N_NODES) return;
    int lane = threadIdx.x & 63;
    int off = offsets[nid], deg = counts[nid];
    float acc[8] = {0, 0, 0, 0, 0, 0, 0, 0};
    int e = 0;
    // 8-deep unroll: 8 independent 16B loads in flight per lane
    for (; e + 7 < deg; e += 8) {
        int s[8];
        #pragma unroll
        for (int u = 0; u < 8; u++) s[u] = esrc[off + e + u];
        uint4 v[8];
        #pragma unroll
        for (int u = 0; u < 8; u++)
            v[u] = *(const uint4*)(Acat + (size_t)s[u] * KTOT + lane * 8);
        #pragma unroll
        for (int u = 0; u < 8; u++) addrow(acc, v[u]);
    }
    for (; e + 3 < deg; e += 4) {
        int s0 = esrc[off + e], s1 = esrc[off + e + 1];
        int s2 = esrc[off + e + 2], s3 = esrc[off + e + 3];
        uint4 v0 = *(const uint4*)(Acat + (size_t)s0 * KTOT + lane * 8);
        uint4 v1 = *(const uint4*)(Acat + (size_t)s1 * KTOT + lane * 8);
        uint4 v2 = *(const uint4*)(Acat + (size_t)s2 * KTOT + lane * 8);
        uint4 v3 = *(const uint4*)(Acat + (size_t)s3 * KTOT + lane * 8);
        addrow(acc, v0); addrow(acc, v1); addrow(acc, v2); addrow(acc, v3);
    }
    for (; e < deg; e++) {
        int s0 = esrc[off + e];
        addrow(acc, *(const uint4*)(Acat + (size_t)s0 * KTOT + lane * 8));
    }
    float scale = (deg > 0) ? (-1.0f / (float)deg) : 0.0f;
    uint4 o;
    o.x = pack2(acc[0] * scale, acc[1] * scale);
    o.y = pack2(acc[2] * scale, acc[3] * scale);
    o.z = pack2(acc[4] * scale, acc[5] * scale);
    o.w = pack2(acc[6] * scale, acc[7] * scale);
    *(uint4*)(Acat + (size_t)nid * KTOT + 512 + lane * 8) = o;
}

// ---------- 6. GEMM: out = Acat @ Wcat^T + b12 (K=1024, masked passthrough) ----------
// Round-2 geometry (BM=BN=256, 8 waves, per-wave 128x64, acc[8][4] -- NO spill) +
// round-3 schedule fixed: BK=32, 4-deep LDS pipeline (4 x 32 KB = 128 KB), ONE sync
// point per K-tile:
//   { ds_read af[8],bf[4]; stage(t+3) into idle buffer; 32 MFMA;
//     lgkm(0); vmcnt(8) [tile t+1 landed; t+2,t+3 in flight]; s_barrier }
// Slack issue->wait ~2.8 iters > HBM latency; vmcnt never drains to 0 mid-loop.
// Swizzle (64-B rows): logical slot l = p ^ ((row>>1)&3). Write side: linear LDS dest,
// source k-offset = ((tid&3)^((tid>>3)&3))*8. Read side: slot = quad ^ ((lr>>1)&3).
// Max 2-way bank aliasing (free, m136).
__global__ __launch_bounds__(512, 2) void gemm_k(const u16* __restrict__ Acat,
                                                 const float* __restrict__ x,
                                                 const u16* __restrict__ Wcat,
                                                 const float* __restrict__ b12,
                                                 const int* __restrict__ counts,
                                                 float* __restrict__ out) {
    __shared__ u16 As[4][BMS * BK];   // 4 x 16 KB
    __shared__ u16 Bs[4][BN * BK];    // 4 x 16 KB   (total 128 KB)

    // XCD swizzle: NWG = 392 = 8*49 exact -> 49 contiguous tiles per XCD;
    // the two N-tiles of one A-panel are consecutive (same XCD L2).
    const int tlin = (blockIdx.x & 7) * (NWG / 8) + (blockIdx.x >> 3);
    const int m0 = (tlin >> 1) * BM;
    const int n0 = (tlin & 1) * BN;

    const int tid  = threadIdx.x;
    const int lane = tid & 63;
    const int wid  = tid >> 6;          // 0..7
    const int wm = wid >> 2, wn = wid & 3;
    const int quad = lane >> 4, lr = lane & 15;

    // staging geometry: per instruction, wave covers 16 rows x 64 B (4 lanes/row).
    // Block chunk q covers rows q*128 + (tid>>2).
    const int rloc  = tid >> 2;                              // 0..127
    const int koffu = (((tid & 3) ^ ((tid >> 3) & 3)) << 3); // pre-swizzled k-slot (u16)
    int arow[2], brow[2];
    #pragma unroll
    for (int q = 0; q < 2; q++) {
        int r = m0 + q * 128 + rloc;
        arow[q] = (r < N_NODES) ? r : (N_NODES - 1);   // clamped filler rows
        brow[q] = n0 + q * 128 + rloc;                 // N exact
    }

    auto stage = [&](int t) {          // 4 loads/wave: 2 A + 2 B
        u16* A_c = &As[t & 3][0]; u16* B_c = &Bs[t & 3][0];
        const int k0 = t * BK;
        #pragma unroll
        for (int q = 0; q < 2; q++)
            gload_lds16(Acat + (size_t)arow[q] * KTOT + k0 + koffu,
                        A_c + q * 4096 + wid * 512);
        #pragma unroll
        for (int q = 0; q < 2; q++)
            gload_lds16(Wcat + (size_t)brow[q] * KTOT + k0 + koffu,
                        B_c + q * 4096 + wid * 512);
    };

    const int rswb = ((lr >> 1) & 3) << 4;   // read-side slot swizzle (bytes)
    auto ldA = [&](const u16* A_c, int mf) -> bf16x8 {
        int row = wm * 128 + mf * 16 + lr;
        return *(const bf16x8*)((const char*)A_c + row * 64 + ((quad << 4) ^ rswb));
    };
    auto ldB = [&](const u16* B_c, int nf) -> bf16x8 {
        int row = wn * 64 + nf * 16 + lr;
        return *(const bf16x8*)((const char*)B_c + row * 64 + ((quad << 4) ^ rswb));
    };

    f32x4 acc[8][4] = {};

    // prologue: tiles 0,1,2 in flight (12 loads); tile 0 = oldest 4 -> vmcnt(8)
    stage(0); stage(1); stage(2);
    S_VMCNT(8);
    __builtin_amdgcn_s_barrier();

    #pragma unroll 1
    for (int t = 0; t < NT; ++t) {
        const u16* A_c = &As[t & 3][0];
        const u16* B_c = &Bs[t & 3][0];

        bf16x8 af[8], bf[4];
        #pragma unroll
        for (int i = 0; i < 8; i++) af[i] = ldA(A_c, i);
        #pragma unroll
        for (int j = 0; j < 4; j++) bf[j] = ldB(B_c, j);

        if (t + 3 < NT) stage(t + 3);     // into buffer (t+3)&3 — idle this iter

        __builtin_amdgcn_s_setprio(1);
        #pragma unroll
        for (int i = 0; i < 8; i++)
            #pragma unroll
            for (int j = 0; j < 4; j++)
                acc[i][j] = __builtin_amdgcn_mfma_f32_16x16x32_bf16(af[i], bf[j], acc[i][j], 0, 0, 0);
        __builtin_amdgcn_s_setprio(0);

        S_LGKM0();                        // my ds_reads of buf t done (region death)
        if (t < NT - 3) {
            S_VMCNT(8);                   // tile t+1 landed; t+2,t+3 stay in flight
            __builtin_amdgcn_s_barrier();
        } else if (t == NT - 3) {
            S_VMCNT(4);                   // tile NT-2 landed; NT-1 in flight
            __builtin_amdgcn_s_barrier();
        } else if (t == NT - 2) {
            S_VMCNT(0);                   // drain: last tile landed
            __builtin_amdgcn_s_barrier();
        }
        // t == NT-1: fall through to epilogue
    }

    // epilogue: C/D layout col=lr, row=quad*4+r ; f32 output, zero-degree passthrough
    #pragma unroll
    for (int i = 0; i < 8; i++) {
        #pragma unroll
        for (int r = 0; r < 4; r++) {
            int grow = m0 + wm * 128 + i * 16 + quad * 4 + r;
            if (grow >= N_NODES) continue;
            int cnt = counts[grow];
            #pragma unroll
            for (int j = 0; j < 4; j++) {
                int gcol = n0 + wn * 64 + j * 16 + lr;
                float v;
                if (cnt > 0) v = acc[i][j][r] + b12[gcol];
                else         v = x[(size_t)grow * DDIM + gcol];   // exact passthrough
                out[(size_t)grow * DDIM + gcol] = v;
            }
        }
    }
}

// ---------- launch ----------
extern "C" void kernel_launch(void* const* d_in, const int* in_sizes, int n_in,
                              void* d_out, int out_size, void* d_ws, size_t ws_size,
                              hipStream_t stream) {
    const float* x  = (const float*)d_in[0];
    const int* src  = (const int*)d_in[1];
    const int* dst  = (const int*)d_in[2];
    const float* W1 = (const float*)d_in[3];
    const float* b1 = (const float*)d_in[4];
    const float* W2 = (const float*)d_in[5];
    const float* b2 = (const float*)d_in[6];
    float* out = (float*)d_out;

    char* ws = (char*)d_ws;
    size_t o = 0;
    auto alloc = [&](size_t bytes) { char* p = ws + o; o += (bytes + 255) & ~(size_t)255; return p; };
    int* counts   = (int*)alloc((size_t)N_NODES * 4);
    int* offsets  = (int*)alloc((size_t)N_NODES * 4);
    int* cursor   = (int*)alloc((size_t)N_NODES * 4);
    int* csum     = (int*)alloc((size_t)NCHUNK * 4);
    int* esrc     = (int*)alloc((size_t)N_EDGES * 4);
    u16* Wcat     = (u16*)alloc((size_t)512 * KTOT * 2);
    float* b12    = (float*)alloc((size_t)512 * 4);
    u16* Acat     = (u16*)alloc((size_t)N_NODES * KTOT * 2);   // [xb | meanNeg], ~102.4 MB
    (void)ws_size; (void)n_in; (void)in_sizes; (void)out_size;

    hipMemsetAsync(counts, 0, (size_t)N_NODES * 4, stream);
    cvt_k<<<(N_NODES * 64) / 256, 256, 0, stream>>>(x, Acat);
    hist_k<<<(N_EDGES + 255) / 256, 256, 0, stream>>>(dst, counts);
    scanA_k<<<NCHUNK, 1024, 0, stream>>>(counts, csum);
    scanB_k<<<1, 64, 0, stream>>>(csum);
    scanC_k<<<NCHUNK, 1024, 0, stream>>>(counts, csum, offsets, cursor);
    fill_k<<<(N_EDGES + 255) / 256, 256, 0, stream>>>(src, dst, cursor, esrc);
    prepw_k<<<(512 * 512) / 256, 256, 0, stream>>>(W1, W2, b1, b2, Wcat, b12);
    agg_k<<<(N_NODES + 3) / 4, 256, 0, stream>>>(Acat, offsets, counts, esrc);
    gemm_k<<<dim3(NWG), 512, 0, stream>>>(Acat, x, Wcat, b12, counts, out);
}